// Round 1
// baseline (1478.068 us; speedup 1.0000x reference)
//
#include <hip/hip_runtime.h>
#include <hip/hip_bf16.h>
#include <math.h>
#include <stdint.h>

// HolomorphicEqProp: spectral-norm'd RNN, 30 recurrent steps.
// B=4096, D_IN=1024, H=1024, D_OUT=256 (hardcoded; steps=30 hardcoded).

#define EPSF 1e-12f

typedef short bf16x8 __attribute__((ext_vector_type(8)));
typedef float f32x4 __attribute__((ext_vector_type(4)));

__device__ __forceinline__ unsigned short f2bf(float f) {
  union { float f; unsigned u; } v; v.f = f;
  unsigned r = v.u + 0x7FFFu + ((v.u >> 16) & 1u);  // round-to-nearest-even
  return (unsigned short)(r >> 16);
}

// async global->LDS, 16B per lane. LDS dest is wave-uniform base + lane*16.
__device__ __forceinline__ void async16(const void* g, void* l) {
  __builtin_amdgcn_global_load_lds(
      (__attribute__((address_space(1))) void*)(uintptr_t)(g),
      (__attribute__((address_space(3))) void*)(unsigned)(uintptr_t)(l),
      16, 0, 0);
}

__device__ __forceinline__ float block_reduce_sum(float x) {
#pragma unroll
  for (int o = 32; o > 0; o >>= 1) x += __shfl_down(x, o, 64);
  __shared__ float sm[8];
  int lane = threadIdx.x & 63, w = threadIdx.x >> 6;
  if (lane == 0) sm[w] = x;
  __syncthreads();
  float t = 0.f;
  if (threadIdx.x == 0) {
    int nw = (int)(blockDim.x >> 6);
    for (int i = 0; i < nw; ++i) t += sm[i];
  }
  return t;
}

// v[j] += sum_{i in block-chunk} W[i,j]*u[i]   (W: MxN row-major)
__global__ void spec_col_partial(const float* __restrict__ W, const float* __restrict__ u,
                                 float* __restrict__ v, int M, int N, int rowsPerBlock) {
  int j = blockIdx.x * blockDim.x + threadIdx.x;
  int i0 = blockIdx.y * rowsPerBlock;
  float acc = 0.f;
  for (int i = i0; i < i0 + rowsPerBlock; ++i)
    acc += W[(size_t)i * N + j] * u[i];
  atomicAdd(&v[j], acc);
}

__global__ void vec_norm2(const float* __restrict__ v, float* __restrict__ out, int n) {
  float acc = 0.f;
  for (int i = threadIdx.x; i < n; i += blockDim.x) { float x = v[i]; acc += x * x; }
  float t = block_reduce_sum(acc);
  if (threadIdx.x == 0) *out = t;
}

// accumulates sum_i (W[i,:]·v)^2  (normalization by (||v||+eps)^2 deferred)
__global__ void spec_row_sq(const float* __restrict__ W, const float* __restrict__ v,
                            float* __restrict__ usq, int N) {
  int i = blockIdx.x;
  float acc = 0.f;
  for (int j = threadIdx.x; j < N; j += blockDim.x)
    acc += W[(size_t)i * N + j] * v[j];
  float r = block_reduce_sum(acc);
  if (threadIdx.x == 0) atomicAdd(usq, r * r);
}

// S: [0..2]=||v||^2, [3..5]=raw sum r_i^2, [6..8]=scale(=1/sigma), [9]=1.0
__global__ void spec_finalize(float* S) {
  int m = threadIdx.x;
  if (m < 3) {
    float nv = sqrtf(S[m]);
    float inv = 1.f / (nv + EPSF);
    float u2sq = S[3 + m] * inv * inv;   // ||u2||^2, u2 = W v_hat
    float nu = sqrtf(u2sq);
    float sigma = u2sq / (nu + EPSF);    // u_hat·u2
    S[6 + m] = 1.f / sigma;
  }
  if (m == 3) S[9] = 1.0f;
}

__global__ void cvt_scaled(const float4* __restrict__ W, const float* __restrict__ sp,
                           ushort4* __restrict__ o, int n4) {
  float s = *sp;
  for (int i = blockIdx.x * blockDim.x + threadIdx.x; i < n4; i += gridDim.x * blockDim.x) {
    float4 w = W[i];
    ushort4 r;
    r.x = f2bf(w.x * s); r.y = f2bf(w.y * s); r.z = f2bf(w.z * s); r.w = f2bf(w.w * s);
    o[i] = r;
  }
}

// h1 = tanh(xproj + b_rec*mod)   (h0 = 0, so the t=0 GEMM is skipped)
__global__ void step0k(const float4* __restrict__ xp, const float4* __restrict__ br,
                       ushort4* __restrict__ h, float mod, int n4, int colmask4) {
  for (int i = blockIdx.x * blockDim.x + threadIdx.x; i < n4; i += gridDim.x * blockDim.x) {
    float4 x = xp[i];
    float4 b = br[i & colmask4];
    ushort4 r;
    r.x = f2bf(tanhf(x.x + b.x * mod));
    r.y = f2bf(tanhf(x.y + b.y * mod));
    r.z = f2bf(tanhf(x.z + b.z * mod));
    r.w = f2bf(tanhf(x.w + b.w * mod));
    h[i] = r;
  }
}

// C = A[M,K] · B[N,K]^T, bf16 in / fp32 accum. 128x128 tile, BK=32,
// 4 waves 2x2, each wave 4x4 frags of mfma_f32_16x16x32_bf16.
// MODE 0: outF = acc + bias[n]
// MODE 1: outBf = bf16(tanh(xproj + (acc + bias[n])*mod))
template <int MODE>
__global__ __launch_bounds__(256) void gemm_bt(
    const unsigned short* __restrict__ A, const unsigned short* __restrict__ B,
    const float* __restrict__ bias, const float* __restrict__ xproj, float mod,
    float* __restrict__ outF, unsigned short* __restrict__ outBf,
    int M, int N, int K) {
  constexpr int BM = 128, BN = 128, BK = 32;
  __shared__ __align__(16) unsigned short As[BM * BK];
  __shared__ __align__(16) unsigned short Bs[BN * BK];
  const int tid = threadIdx.x;
  const int wave = tid >> 6, lane = tid & 63;
  const int m0 = blockIdx.x * BM, n0 = blockIdx.y * BN;
  const int wm = (wave >> 1) * 64, wn = (wave & 1) * 64;
  const int lrow = lane & 15, quad = lane >> 4;

  f32x4 acc[4][4] = {};

  for (int k0 = 0; k0 < K; k0 += BK) {
#pragma unroll
    for (int inst = 0; inst < 2; ++inst) {
      int e = inst * 2048 + tid * 8;       // element offset in 128x32 tile
      int r = e >> 5, c = e & 31;
      async16(&A[(size_t)(m0 + r) * K + k0 + c], &As[e]);
      async16(&B[(size_t)(n0 + r) * K + k0 + c], &Bs[e]);
    }
    __syncthreads();  // drains vmcnt(0) for the LDS-DMA + barrier

    bf16x8 af[4], bfr[4];
#pragma unroll
    for (int i = 0; i < 4; ++i) {
      af[i]  = *(const bf16x8*)&As[(wm + i * 16 + lrow) * BK + quad * 8];
      bfr[i] = *(const bf16x8*)&Bs[(wn + i * 16 + lrow) * BK + quad * 8];
    }
#pragma unroll
    for (int i = 0; i < 4; ++i)
#pragma unroll
      for (int j = 0; j < 4; ++j)
        acc[i][j] = __builtin_amdgcn_mfma_f32_16x16x32_bf16(af[i], bfr[j], acc[i][j], 0, 0, 0);
    __syncthreads();
  }

#pragma unroll
  for (int i = 0; i < 4; ++i) {
#pragma unroll
    for (int j = 0; j < 4; ++j) {
      int col = n0 + wn + j * 16 + lrow;
      float bv = bias[col];
#pragma unroll
      for (int r = 0; r < 4; ++r) {
        int row = m0 + wm + i * 16 + quad * 4 + r;
        size_t idx = (size_t)row * N + col;
        float val = acc[i][j][r] + bv;
        if (MODE == 1) {
          outBf[idx] = f2bf(tanhf(xproj[idx] + val * mod));
        } else {
          outF[idx] = val;
        }
      }
    }
  }
}

extern "C" void kernel_launch(void* const* d_in, const int* in_sizes, int n_in,
                              void* d_out, int out_size, void* d_ws, size_t ws_size,
                              hipStream_t stream) {
  const float* x     = (const float*)d_in[0];
  const float* W_in  = (const float*)d_in[1];
  const float* b_in  = (const float*)d_in[2];
  const float* W_rec = (const float*)d_in[3];
  const float* b_rec = (const float*)d_in[4];
  const float* W_out = (const float*)d_in[5];
  const float* b_out = (const float*)d_in[6];
  const float* u_in  = (const float*)d_in[7];
  const float* u_rec = (const float*)d_in[8];
  const float* u_out = (const float*)d_in[9];

  const int B = 4096, DIN = 1024, H = 1024, DOUT = 256, STEPS = 30;

  char* w = (char*)d_ws;
  float* S = (float*)w;                  // scalars [0..15]
  float* v_in = S + 256;                 // 1024 f32
  float* v_rec = v_in + 1024;
  float* v_out = v_rec + 1024;
  unsigned short* Wi_bf = (unsigned short*)(w + (1 << 14));
  unsigned short* Wr_bf = Wi_bf + (size_t)H * DIN;
  unsigned short* Wo_bf = Wr_bf + (size_t)H * H;
  unsigned short* x_bf  = Wo_bf + (size_t)DOUT * H;
  float* xproj = (float*)(x_bf + (size_t)B * DIN);
  unsigned short* hA = (unsigned short*)(xproj + (size_t)B * H);
  unsigned short* hB = hA + (size_t)B * H;

  hipMemsetAsync(w, 0, 1 << 14, stream);  // zero scalars + v buffers

  dim3 t256(256);
  // --- spectral norms (fp32, exact per reference) ---
  spec_col_partial<<<dim3(DIN / 256, H / 64), t256, 0, stream>>>(W_in, u_in, v_in, H, DIN, 64);
  spec_col_partial<<<dim3(H / 256, H / 64), t256, 0, stream>>>(W_rec, u_rec, v_rec, H, H, 64);
  spec_col_partial<<<dim3(H / 256, DOUT / 64), t256, 0, stream>>>(W_out, u_out, v_out, DOUT, H, 64);
  vec_norm2<<<1, t256, 0, stream>>>(v_in, &S[0], DIN);
  vec_norm2<<<1, t256, 0, stream>>>(v_rec, &S[1], H);
  vec_norm2<<<1, t256, 0, stream>>>(v_out, &S[2], H);
  spec_row_sq<<<H, t256, 0, stream>>>(W_in, v_in, &S[3], DIN);
  spec_row_sq<<<H, t256, 0, stream>>>(W_rec, v_rec, &S[4], H);
  spec_row_sq<<<DOUT, t256, 0, stream>>>(W_out, v_out, &S[5], H);
  spec_finalize<<<1, 64, 0, stream>>>(S);

  // --- convert weights (scale folded) and x to bf16 ---
  cvt_scaled<<<512, t256, 0, stream>>>((const float4*)W_in, &S[6], (ushort4*)Wi_bf, H * DIN / 4);
  cvt_scaled<<<512, t256, 0, stream>>>((const float4*)W_rec, &S[7], (ushort4*)Wr_bf, H * H / 4);
  cvt_scaled<<<128, t256, 0, stream>>>((const float4*)W_out, &S[8], (ushort4*)Wo_bf, DOUT * H / 4);
  cvt_scaled<<<1024, t256, 0, stream>>>((const float4*)x, &S[9], (ushort4*)x_bf, B * DIN / 4);

  // --- x_proj = x @ Wi_n^T + b_in (fp32 out) ---
  gemm_bt<0><<<dim3(B / 128, H / 128), t256, 0, stream>>>(
      x_bf, Wi_bf, b_in, nullptr, 0.f, xproj, nullptr, B, H, DIN);

  // --- step t=0 (h=0): h = tanh(xproj + b_rec*mod0), mod0 = 1+0.1*sin(0) = 1 ---
  step0k<<<2048, t256, 0, stream>>>((const float4*)xproj, (const float4*)b_rec,
                                    (ushort4*)hA, 1.0f, B * H / 4, H / 4 - 1);

  // --- steps t=1..29 ---
  unsigned short* cur = hA;
  unsigned short* nxt = hB;
  for (int t = 1; t < STEPS; ++t) {
    float mod = 1.0f + 0.1f * (float)sin(0.3 * (double)t);
    gemm_bt<1><<<dim3(B / 128, H / 128), t256, 0, stream>>>(
        cur, Wr_bf, b_rec, xproj, mod, nullptr, nxt, B, H, H);
    unsigned short* tmp = cur; cur = nxt; nxt = tmp;
  }

  // --- out = h @ Wo_n^T + b_out (fp32 to d_out) ---
  gemm_bt<0><<<dim3(B / 128, DOUT / 128), t256, 0, stream>>>(
      cur, Wo_bf, b_out, nullptr, 0.f, (float*)d_out, nullptr, B, DOUT, H);
}